// Round 9
// baseline (209.895 us; speedup 1.0000x reference)
//
#include <hip/hip_runtime.h>
#include <hip/hip_bf16.h>

#define DEV static __device__ __forceinline__

constexpr int B=16, N=128, FIN=128, FOUT=256, EOUT=64, BINW=14, BOUT=64, CI=64, L1=256;

// ---- scratch layout in d_ws (float offsets) ----
constexpr int O_H   = 0;                       // [B,N,FOUT]
constexpr int O_S   = O_H  + B*N*FOUT;         // [B,N]
constexpr int O_SU  = O_S  + B*N;
constexpr int O_SV  = O_SU + B*N;
constexpr int O_ATT = O_SV + B*N;              // [B,N,N]
constexpr int O_ZF  = O_ATT+ B*N*N;            // [B,N,CI]
constexpr int O_ZB  = O_ZF + B*N*CI;
constexpr int O_RF  = O_ZB + B*N*CI;
constexpr int O_RB  = O_RF + B*N*CI;
constexpr int O_H1  = O_RB + B*N*CI;           // [B,N,FOUT]

DEV float bf16_to_f32(unsigned short u){
  unsigned int x = ((unsigned int)u) << 16; float f;
  __builtin_memcpy(&f, &x, 4); return f;
}
DEV void bf2x(unsigned int u, float& lo, float& hi){
  unsigned int a = u << 16, b = u & 0xFFFF0000u;
  __builtin_memcpy(&lo, &a, 4); __builtin_memcpy(&hi, &b, 4);
}
DEV float lrelu(float x){ return x > 0.f ? x : 0.01f * x; }
DEV float bcastf(float v, int lane){
  return __builtin_bit_cast(float, __builtin_amdgcn_readlane(__builtin_bit_cast(int, v), lane));
}
DEV float ldf(const void* p, int i, int m){
  return m ? bf16_to_f32(((const unsigned short*)p)[i]) : ((const float*)p)[i];
}
// block-parallel dtype detect (bf16 ~100% of sampled exps in [100,140]; f32 ~58%)
DEV int blk_mode(const void* x, int nt, int tid){
  const unsigned short* u = (const unsigned short*)x;
  int e = (u[tid & 255] >> 7) & 0xFF;
  int cnt = __syncthreads_count(e >= 100 && e <= 140);
  return cnt * 4 >= nt * 3;
}

// K1: h = x@W ; s = h·fcc_w ; P,Q (LDS only) ; su/sv fused (sv[r]==sv[r+64])
__global__ __launch_bounds__(256) void k_h_pq(const void* __restrict__ xr,
                                              const void* __restrict__ Wp,
                                              const void* __restrict__ Ap,
                                              const void* __restrict__ fccwp,
                                              const void* __restrict__ fcwp,
                                              float* __restrict__ ws){
  int blk = blockIdx.x, tid = threadIdx.x;
  int b = blk >> 4, i0 = (blk & 15) * 8;
  __shared__ __align__(16) float xl[8*FIN];
  __shared__ __align__(16) float hrow[8*FOUT];
  __shared__ __align__(16) float pl[8*EOUT];
  __shared__ __align__(16) float ql[8*EOUT];
  __shared__ float red[32];
  int mode = blk_mode(xr, 256, tid);
  if (mode){
    const unsigned short* xu = (const unsigned short*)xr + (size_t)(b*N + i0)*FIN;
    for (int t = tid; t < 8*FIN/8; t += 256){
      uint4 u4 = ((const uint4*)xu)[t];
      float* o = &xl[t*8];
      bf2x(u4.x,o[0],o[1]); bf2x(u4.y,o[2],o[3]); bf2x(u4.z,o[4],o[5]); bf2x(u4.w,o[6],o[7]);
    }
  } else {
    const float* xf = (const float*)xr + (size_t)(b*N + i0)*FIN;
    for (int t4 = tid; t4 < 8*FIN/4; t4 += 256)
      *(float4*)&xl[t4*4] = ((const float4*)xf)[t4];
  }
  __syncthreads();
  int f = tid;
  float acc[8] = {0,0,0,0,0,0,0,0};
  if (mode){
    const unsigned short* Wu = (const unsigned short*)Wp;
    for (int c = 0; c < FIN; c += 4){
      float w0 = bf16_to_f32(Wu[(c+0)*FOUT + f]);
      float w1 = bf16_to_f32(Wu[(c+1)*FOUT + f]);
      float w2 = bf16_to_f32(Wu[(c+2)*FOUT + f]);
      float w3 = bf16_to_f32(Wu[(c+3)*FOUT + f]);
      #pragma unroll
      for (int r = 0; r < 8; ++r){
        float4 x4 = *(const float4*)&xl[r*FIN + c];
        acc[r] += x4.x*w0 + x4.y*w1 + x4.z*w2 + x4.w*w3;
      }
    }
  } else {
    const float* Wf = (const float*)Wp;
    for (int c = 0; c < FIN; c += 4){
      float w0 = Wf[(c+0)*FOUT + f];
      float w1 = Wf[(c+1)*FOUT + f];
      float w2 = Wf[(c+2)*FOUT + f];
      float w3 = Wf[(c+3)*FOUT + f];
      #pragma unroll
      for (int r = 0; r < 8; ++r){
        float4 x4 = *(const float4*)&xl[r*FIN + c];
        acc[r] += x4.x*w0 + x4.y*w1 + x4.z*w2 + x4.w*w3;
      }
    }
  }
  float fw = ldf(fccwp, f, mode);
  #pragma unroll
  for (int r = 0; r < 8; ++r){
    ws[O_H + (b*N + i0 + r)*FOUT + f] = acc[r];
    hrow[r*FOUT + f] = acc[r];
  }
  #pragma unroll
  for (int r = 0; r < 8; ++r){
    float v = acc[r] * fw;
    for (int off = 32; off; off >>= 1) v += __shfl_down(v, off);
    if ((tid & 63) == 0) red[(tid >> 6)*8 + r] = v;
  }
  __syncthreads();
  if (tid < 8){
    float s = red[tid] + red[8+tid] + red[16+tid] + red[24+tid];
    ws[O_S + b*N + i0 + tid] = s;
  }
  // P/Q into LDS (4 waves: which = P/Q, hh = row-half); hrow reads wave-uniform
  {
    int o = tid & 63, which = (tid >> 6) & 1, hh = tid >> 7;
    float a4[4] = {0.f,0.f,0.f,0.f};
    if (mode){
      const unsigned short* Au = (const unsigned short*)Ap;
      for (int c = 0; c < FOUT; c += 4){
        float w0 = bf16_to_f32(Au[(which*FOUT + c+0)*EOUT + o]);
        float w1 = bf16_to_f32(Au[(which*FOUT + c+1)*EOUT + o]);
        float w2 = bf16_to_f32(Au[(which*FOUT + c+2)*EOUT + o]);
        float w3 = bf16_to_f32(Au[(which*FOUT + c+3)*EOUT + o]);
        #pragma unroll
        for (int r = 0; r < 4; ++r){
          float4 h4 = *(const float4*)&hrow[(hh*4+r)*FOUT + c];
          a4[r] += h4.x*w0 + h4.y*w1 + h4.z*w2 + h4.w*w3;
        }
      }
    } else {
      const float* Af = (const float*)Ap;
      for (int c = 0; c < FOUT; c += 4){
        float w0 = Af[(which*FOUT + c+0)*EOUT + o];
        float w1 = Af[(which*FOUT + c+1)*EOUT + o];
        float w2 = Af[(which*FOUT + c+2)*EOUT + o];
        float w3 = Af[(which*FOUT + c+3)*EOUT + o];
        #pragma unroll
        for (int r = 0; r < 4; ++r){
          float4 h4 = *(const float4*)&hrow[(hh*4+r)*FOUT + c];
          a4[r] += h4.x*w0 + h4.y*w1 + h4.z*w2 + h4.w*w3;
        }
      }
    }
    float* dst = which ? ql : pl;
    #pragma unroll
    for (int r = 0; r < 4; ++r) dst[(hh*4+r)*EOUT + o] = a4[r];
  }
  __syncthreads();
  // su for rows i0..i0+7 ; sv for pairs (value keyed by j2=(2r)&127; sv[r]==sv[r+64])
  {
    int o = tid & 63, w = tid >> 6;
    float fw2 = ldf(fcwp, o, mode);
    float s1 = lrelu(pl[w*EOUT + o]     + ql[w*EOUT + o])     * fw2;
    float s2 = lrelu(pl[(w+4)*EOUT + o] + ql[(w+4)*EOUT + o]) * fw2;
    float s3 = lrelu(pl[(2*w)*EOUT + o] + ql[(2*w+1)*EOUT + o]) * fw2;
    for (int off = 32; off; off >>= 1){
      s1 += __shfl_down(s1, off); s2 += __shfl_down(s2, off); s3 += __shfl_down(s3, off);
    }
    if (o == 0){
      ws[O_SU + b*N + i0 + w]     = s1;
      ws[O_SU + b*N + i0 + w + 4] = s2;
      int r1 = (i0 + 2*w) >> 1;
      ws[O_SV + b*N + r1]      = s3;
      ws[O_SV + b*N + r1 + 64] = s3;
    }
  }
}

struct AttArgs { const void *we,*x,*wfcw,*wfcb,*fcw,*fcb,*fccb,*wihf,*bihf,*bhhf,*wihb,*bihb,*bhhb; };

// K2: per block: TWO (b,i) rows. edge-MLP + mask + softmax (no max-sub: masked
// lanes underflow to exp->0; unmasked |e|~O(1)) -> att ; hn_pre ; z
__global__ __launch_bounds__(256) void k_att(AttArgs A, const int* __restrict__ adj,
                                             float* __restrict__ ws){
  int blk = blockIdx.x, tid = threadIdx.x;
  int half = tid >> 7, j = tid & 127, wv = (tid >> 6) & 1;
  int tau = blk*2 + half;
  int b = tau >> 7, i = tau & 127;
  __shared__ __align__(16) float wel[2][N*BINW];
  __shared__ __align__(16) float hnp[2][N];
  __shared__ __align__(16) float wfcwl[BINW*BOUT];
  __shared__ __align__(16) float wfcbl[BOUT];
  __shared__ __align__(16) float fcw2l[BOUT];
  __shared__ float red2[2][2];
  int mode = blk_mode(A.x, 256, tid);
  for (int t = tid; t < BINW*BOUT; t += 256) wfcwl[t] = ldf(A.wfcw, t, mode);
  if (tid < BOUT){ wfcbl[tid] = ldf(A.wfcb, tid, mode); fcw2l[tid] = ldf(A.fcw, EOUT + tid, mode); }
  if (mode){
    const unsigned short* weu = (const unsigned short*)A.we + (size_t)(b*N + i)*N*BINW;
    for (int t = j; t < N*BINW/8; t += 128){
      uint4 q = ((const uint4*)weu)[t];
      float* o = &wel[half][t*8];
      bf2x(q.x,o[0],o[1]); bf2x(q.y,o[2],o[3]); bf2x(q.z,o[4],o[5]); bf2x(q.w,o[6],o[7]);
    }
  } else {
    const float* wef = (const float*)A.we + (size_t)(b*N + i)*N*BINW;
    for (int t4 = j; t4 < N*BINW/4; t4 += 128)
      *(float4*)&wel[half][t4*4] = ((const float4*)wef)[t4];
  }
  __syncthreads();
  float wr[BINW];
  #pragma unroll
  for (int t = 0; t < BINW; ++t) wr[t] = wel[half][j*BINW + t];
  float wcon = 0.f;
  for (int o = 0; o < BOUT; o += 4){
    float4 bb = *(const float4*)&wfcbl[o];
    float w0 = bb.x, w1 = bb.y, w2 = bb.z, w3 = bb.w;
    #pragma unroll
    for (int t = 0; t < BINW; ++t){
      float4 w4 = *(const float4*)&wfcwl[t*BOUT + o];
      w0 = fmaf(wr[t], w4.x, w0); w1 = fmaf(wr[t], w4.y, w1);
      w2 = fmaf(wr[t], w4.z, w2); w3 = fmaf(wr[t], w4.w, w3);
    }
    float4 f4 = *(const float4*)&fcw2l[o];
    wcon += lrelu(w0)*f4.x + lrelu(w1)*f4.y + lrelu(w2)*f4.z + lrelu(w3)*f4.w;
  }
  const float* R = ws;
  float econ = (i < 64) ? R[O_SU + b*N + 2*i + (j >= 64 ? 1 : 0)]
                        : R[O_SV + b*N + j];
  float etot = econ + wcon + ldf(A.fcb, 0, mode);
  float m = (adj[(b*N + i)*N + j] > 0) ? etot : -9e15f;
  float ev = __expf(m);                 // masked -> exactly 0
  float sum = ev;
  for (int off = 32; off; off >>= 1) sum += __shfl_xor(sum, off);
  if ((tid & 63) == 0) red2[half][wv] = sum;
  __syncthreads();
  sum = red2[half][0] + red2[half][1];
  float att = ev / sum;
  ws[O_ATT + (b*N + i)*N + j] = att;
  float sbi = R[O_S + b*N + i];
  hnp[half][j] = lrelu(att * sbi + ldf(A.fccb, 0, mode));
  __syncthreads();
  // z[b,i,c] both directions (per half: 2 waves = 2 directions)
  {
    int d = wv, c = tid & 63;
    float acc = ldf(d ? A.bihb : A.bihf, c, mode) + ldf(d ? A.bhhb : A.bhhf, c, mode);
    const void* wihp = d ? A.wihb : A.wihf;
    if (mode){
      const uint4* wq = (const uint4*)((const unsigned short*)wihp + c*N);
      #pragma unroll 4
      for (int k = 0; k < N; k += 8){
        uint4 q = wq[k >> 3];
        float w0,w1,w2,w3,w4,w5,w6,w7;
        bf2x(q.x,w0,w1); bf2x(q.y,w2,w3); bf2x(q.z,w4,w5); bf2x(q.w,w6,w7);
        float4 h0 = *(const float4*)&hnp[half][k];
        float4 h1 = *(const float4*)&hnp[half][k+4];
        acc += h0.x*w0 + h0.y*w1 + h0.z*w2 + h0.w*w3
             + h1.x*w4 + h1.y*w5 + h1.z*w6 + h1.w*w7;
      }
    } else {
      const float* wf = (const float*)wihp + c*N;
      #pragma unroll 8
      for (int k = 0; k < N; k += 4){
        float4 h4 = *(const float4*)&hnp[half][k];
        float4 w4 = *(const float4*)&wf[k];
        acc += h4.x*w4.x + h4.y*w4.y + h4.z*w4.z + h4.w*w4.w;
      }
    }
    ws[(d ? O_ZB : O_ZF) + (b*N + i)*CI + c] = acc;
  }
}

// K3: blocks 0..31: serial RNN chains (wave 0).  blocks 32..255: h1 = att@h.
// RNN broadcast is hybrid: low 32 h-values via batched v_readlane (VALU pipe),
// high 32 via uniform ds_read_b128 from an LDS mirror (DS pipe) -> the two
// issue streams overlap and the LDS latency hides under readlane+FMA issue.
__global__ __launch_bounds__(256, 1) void k_rnn_h1(const void* __restrict__ xr,
                                                   const void* __restrict__ whhf,
                                                   const void* __restrict__ whhb,
                                                   float* __restrict__ ws){
  __shared__ __align__(16) float sh[N*CI];   // rnn: z/h buffer (32 KB); h1: attT (first 4 KB)
  __shared__ __align__(16) float hl[CI];     // rnn: h mirror for DS-broadcast half
  int blk = blockIdx.x, tid = threadIdx.x;
  int mode = blk_mode(xr, 256, tid);
  const float* R = ws;
  if (blk < 32){
    int d = blk >> 4, b = blk & 15;
    const int zb = (d ? O_ZB : O_ZF) + b*N*CI;
    const int ob = (d ? O_RB : O_RF) + b*N*CI;
    for (int it = tid; it < N*CI/4; it += 256)
      *(float4*)&sh[it*4] = *(const float4*)&ws[zb + it*4];
    __syncthreads();
    if (tid < 64){
      int c = tid;
      const void* whhp = d ? whhb : whhf;
      float wreg[CI];
      if (mode){
        const uint4* wq = (const uint4*)((const unsigned short*)whhp + c*CI);
        #pragma unroll
        for (int k = 0; k < CI; k += 8){
          uint4 q = wq[k >> 3];
          bf2x(q.x,wreg[k+0],wreg[k+1]); bf2x(q.y,wreg[k+2],wreg[k+3]);
          bf2x(q.z,wreg[k+4],wreg[k+5]); bf2x(q.w,wreg[k+6],wreg[k+7]);
        }
      } else {
        const float* wf = (const float*)whhp + c*CI;
        #pragma unroll
        for (int k = 0; k < CI; k += 4){
          float4 w4 = *(const float4*)&wf[k];
          wreg[k]=w4.x; wreg[k+1]=w4.y; wreg[k+2]=w4.z; wreg[k+3]=w4.w;
        }
      }
      hl[c] = 0.f;                 // single wave: DS ops in-order, no barrier needed
      const int step = d ? -1 : 1;
      int tt = d ? (N-1) : 0;
      float hv = 0.f;
      float z = sh[tt*CI + c];
      for (int t = 0; t < N; ++t){
        int ti = tt + step; ti = ti < 0 ? 0 : (ti > N-1 ? N-1 : ti);
        float znext = sh[ti*CI + c];          // prefetch next z (DS pipe)
        // high half h[32..63] via uniform LDS reads (issued early, latency hidden)
        float4 hq0 = *(const float4*)&hl[32];
        float4 hq1 = *(const float4*)&hl[36];
        float4 hq2 = *(const float4*)&hl[40];
        float4 hq3 = *(const float4*)&hl[44];
        float4 hq4 = *(const float4*)&hl[48];
        float4 hq5 = *(const float4*)&hl[52];
        float4 hq6 = *(const float4*)&hl[56];
        float4 hq7 = *(const float4*)&hl[60];
        // low half h[0..31] via batched readlane (VALU pipe)
        float s[32];
        #pragma unroll
        for (int k = 0; k < 32; ++k) s[k] = bcastf(hv, k);
        float a0 = z, a1 = 0.f, a2 = 0.f, a3 = 0.f;
        #pragma unroll
        for (int k = 0; k < 32; k += 4){
          a0 = fmaf(s[k+0], wreg[k+0], a0);
          a1 = fmaf(s[k+1], wreg[k+1], a1);
          a2 = fmaf(s[k+2], wreg[k+2], a2);
          a3 = fmaf(s[k+3], wreg[k+3], a3);
        }
        a0 = fmaf(hq0.x, wreg[32], a0); a1 = fmaf(hq0.y, wreg[33], a1);
        a2 = fmaf(hq0.z, wreg[34], a2); a3 = fmaf(hq0.w, wreg[35], a3);
        a0 = fmaf(hq1.x, wreg[36], a0); a1 = fmaf(hq1.y, wreg[37], a1);
        a2 = fmaf(hq1.z, wreg[38], a2); a3 = fmaf(hq1.w, wreg[39], a3);
        a0 = fmaf(hq2.x, wreg[40], a0); a1 = fmaf(hq2.y, wreg[41], a1);
        a2 = fmaf(hq2.z, wreg[42], a2); a3 = fmaf(hq2.w, wreg[43], a3);
        a0 = fmaf(hq3.x, wreg[44], a0); a1 = fmaf(hq3.y, wreg[45], a1);
        a2 = fmaf(hq3.z, wreg[46], a2); a3 = fmaf(hq3.w, wreg[47], a3);
        a0 = fmaf(hq4.x, wreg[48], a0); a1 = fmaf(hq4.y, wreg[49], a1);
        a2 = fmaf(hq4.z, wreg[50], a2); a3 = fmaf(hq4.w, wreg[51], a3);
        a0 = fmaf(hq5.x, wreg[52], a0); a1 = fmaf(hq5.y, wreg[53], a1);
        a2 = fmaf(hq5.z, wreg[54], a2); a3 = fmaf(hq5.w, wreg[55], a3);
        a0 = fmaf(hq6.x, wreg[56], a0); a1 = fmaf(hq6.y, wreg[57], a1);
        a2 = fmaf(hq6.z, wreg[58], a2); a3 = fmaf(hq6.w, wreg[59], a3);
        a0 = fmaf(hq7.x, wreg[60], a0); a1 = fmaf(hq7.y, wreg[61], a1);
        a2 = fmaf(hq7.z, wreg[62], a2); a3 = fmaf(hq7.w, wreg[63], a3);
        float x = (a0+a1)+(a2+a3);
        x = fminf(15.f, fmaxf(-15.f, x));
        float p = __expf(2.f * x);
        hv = (p - 1.f) * __builtin_amdgcn_rcpf(p + 1.f);
        hl[c] = hv;                 // mirror for next step's DS-broadcast half
        sh[tt*CI + c] = hv;
        z = znext;
        tt += step;
      }
    }
    __syncthreads();
    for (int it = tid; it < N*CI/4; it += 256)
      *(float4*)&ws[ob + it*4] = *(const float4*)&sh[it*4];
  } else {
    for (int task = blk - 32; task < 256; task += 224){
      int b = task >> 4, i0 = (task & 15) * 8;
      int f = tid;
      __syncthreads();
      for (int t = tid; t < 8*N; t += 256){
        int r = t >> 7, k = t & 127;
        sh[k*8 + r] = R[O_ATT + (b*N + i0 + r)*N + k];
      }
      __syncthreads();
      float acc[8] = {0,0,0,0,0,0,0,0};
      for (int k = 0; k < N; ++k){
        float hv = R[O_H + (b*N + k)*FOUT + f];
        float4 a0 = *(const float4*)&sh[k*8];
        float4 a1 = *(const float4*)&sh[k*8 + 4];
        acc[0] += a0.x*hv; acc[1] += a0.y*hv; acc[2] += a0.z*hv; acc[3] += a0.w*hv;
        acc[4] += a1.x*hv; acc[5] += a1.y*hv; acc[6] += a1.z*hv; acc[7] += a1.w*hv;
      }
      #pragma unroll
      for (int r = 0; r < 8; ++r)
        ws[O_H1 + (b*N + i0 + r)*FOUT + f] = acc[r];
    }
  }
}

// K4: out = elu(cat(lrelu(rf), lrelu(rb), h1) @ fco_w + fco_b), 8 rows/block
__global__ __launch_bounds__(256) void k_out(const void* __restrict__ xr,
                                             const void* __restrict__ fcowp,
                                             const void* __restrict__ fcobp,
                                             const float* __restrict__ R, void* dout){
  int blk = blockIdx.x, tid = threadIdx.x;
  int b = blk >> 4, i0 = (blk & 15) * 8;
  constexpr int KW = 2*CI + FOUT;  // 416
  __shared__ __align__(16) float inl[8*KW];
  int mode = blk_mode(xr, 256, tid);
  for (int t = tid; t < 8*2*CI; t += 256){
    int r = t >> 7, k = t & 127;
    int row = b*N + i0 + r;
    inl[r*KW + k] = (k < CI) ? lrelu(R[O_RF + row*CI + k])
                             : lrelu(R[O_RB + row*CI + (k - CI)]);
  }
  for (int t = tid; t < 8*FOUT; t += 256){
    int r = t >> 8, k = t & 255;
    inl[r*KW + 2*CI + k] = R[O_H1 + (b*N + i0 + r)*FOUT + k];
  }
  __syncthreads();
  int l = tid;
  float bias = ldf(fcobp, l, mode);
  float acc[8];
  #pragma unroll
  for (int r = 0; r < 8; ++r) acc[r] = bias;
  if (mode){
    const unsigned short* fu = (const unsigned short*)fcowp;
    for (int k = 0; k < KW; k += 4){
      float w0 = bf16_to_f32(fu[(k+0)*L1 + l]);
      float w1 = bf16_to_f32(fu[(k+1)*L1 + l]);
      float w2 = bf16_to_f32(fu[(k+2)*L1 + l]);
      float w3 = bf16_to_f32(fu[(k+3)*L1 + l]);
      #pragma unroll
      for (int r = 0; r < 8; ++r){
        float4 v = *(const float4*)&inl[r*KW + k];
        acc[r] += v.x*w0 + v.y*w1 + v.z*w2 + v.w*w3;
      }
    }
  } else {
    const float* ff = (const float*)fcowp;
    for (int k = 0; k < KW; k += 4){
      float w0 = ff[(k+0)*L1 + l];
      float w1 = ff[(k+1)*L1 + l];
      float w2 = ff[(k+2)*L1 + l];
      float w3 = ff[(k+3)*L1 + l];
      #pragma unroll
      for (int r = 0; r < 8; ++r){
        float4 v = *(const float4*)&inl[r*KW + k];
        acc[r] += v.x*w0 + v.y*w1 + v.z*w2 + v.w*w3;
      }
    }
  }
  #pragma unroll
  for (int r = 0; r < 8; ++r){
    float o = acc[r] > 0.f ? acc[r] : expm1f(acc[r]);
    int idx = (b*N + i0 + r)*L1 + l;
    if (mode) ((__hip_bfloat16*)dout)[idx] = __float2bfloat16(o);
    else      ((float*)dout)[idx] = o;
  }
}

extern "C" void kernel_launch(void* const* d_in, const int* in_sizes, int n_in,
                              void* d_out, int out_size, void* d_ws, size_t ws_size,
                              hipStream_t stream){
  (void)in_sizes; (void)n_in; (void)out_size; (void)ws_size;
  float* ws = (float*)d_ws;
  AttArgs A;
  A.we = d_in[2]; A.x = d_in[0]; A.wfcw = d_in[5]; A.wfcb = d_in[6];
  A.fcw = d_in[7]; A.fcb = d_in[8]; A.fccb = d_in[10];
  A.wihf = d_in[11]; A.bihf = d_in[13]; A.bhhf = d_in[14];
  A.wihb = d_in[15]; A.bihb = d_in[17]; A.bhhb = d_in[18];
  hipLaunchKernelGGL(k_h_pq,   dim3(256),    dim3(256), 0, stream,
                     d_in[0], d_in[3], d_in[4], d_in[9], d_in[7], ws);
  hipLaunchKernelGGL(k_att,    dim3(B*N/2),  dim3(256), 0, stream, A, (const int*)d_in[1], ws);
  hipLaunchKernelGGL(k_rnn_h1, dim3(256),    dim3(256), 0, stream,
                     d_in[0], d_in[12], d_in[16], ws);
  hipLaunchKernelGGL(k_out,    dim3(256),    dim3(256), 0, stream,
                     d_in[0], d_in[19], d_in[20], ws, d_out);
}

// Round 10
// 204.590 us; speedup vs baseline: 1.0259x; 1.0259x over previous
//
#include <hip/hip_runtime.h>
#include <hip/hip_bf16.h>

#define DEV static __device__ __forceinline__

constexpr int B=16, N=128, FIN=128, FOUT=256, EOUT=64, BINW=14, BOUT=64, CI=64, L1=256;

// ---- scratch layout in d_ws (float offsets) ----
constexpr int O_H   = 0;                       // [B,N,FOUT]
constexpr int O_S   = O_H  + B*N*FOUT;         // [B,N]
constexpr int O_SU  = O_S  + B*N;
constexpr int O_SV  = O_SU + B*N;
constexpr int O_ATT = O_SV + B*N;              // [B,N,N]
constexpr int O_ZF  = O_ATT+ B*N*N;            // [B,N,CI]
constexpr int O_ZB  = O_ZF + B*N*CI;
constexpr int O_RF  = O_ZB + B*N*CI;
constexpr int O_RB  = O_RF + B*N*CI;
constexpr int O_H1  = O_RB + B*N*CI;           // [B,N,FOUT]

DEV float bf16_to_f32(unsigned short u){
  unsigned int x = ((unsigned int)u) << 16; float f;
  __builtin_memcpy(&f, &x, 4); return f;
}
DEV void bf2x(unsigned int u, float& lo, float& hi){
  unsigned int a = u << 16, b = u & 0xFFFF0000u;
  __builtin_memcpy(&lo, &a, 4); __builtin_memcpy(&hi, &b, 4);
}
DEV float lrelu(float x){ return x > 0.f ? x : 0.01f * x; }
DEV float bcastf(float v, int lane){
  return __builtin_bit_cast(float, __builtin_amdgcn_readlane(__builtin_bit_cast(int, v), lane));
}
DEV float ldf(const void* p, int i, int m){
  return m ? bf16_to_f32(((const unsigned short*)p)[i]) : ((const float*)p)[i];
}
// block-parallel dtype detect (bf16 ~100% of sampled exps in [100,140]; f32 ~58%)
DEV int blk_mode(const void* x, int nt, int tid){
  const unsigned short* u = (const unsigned short*)x;
  int e = (u[tid & 255] >> 7) & 0xFF;
  int cnt = __syncthreads_count(e >= 100 && e <= 140);
  return cnt * 4 >= nt * 3;
}

// K1: h = x@W ; s = h·fcc_w ; P,Q (LDS only) ; su/sv fused (sv[r]==sv[r+64])
__global__ __launch_bounds__(256) void k_h_pq(const void* __restrict__ xr,
                                              const void* __restrict__ Wp,
                                              const void* __restrict__ Ap,
                                              const void* __restrict__ fccwp,
                                              const void* __restrict__ fcwp,
                                              float* __restrict__ ws){
  int blk = blockIdx.x, tid = threadIdx.x;
  int b = blk >> 4, i0 = (blk & 15) * 8;
  __shared__ __align__(16) float xl[8*FIN];
  __shared__ __align__(16) float hrow[8*FOUT];
  __shared__ __align__(16) float pl[8*EOUT];
  __shared__ __align__(16) float ql[8*EOUT];
  __shared__ float red[32];
  int mode = blk_mode(xr, 256, tid);
  if (mode){
    const unsigned short* xu = (const unsigned short*)xr + (size_t)(b*N + i0)*FIN;
    for (int t = tid; t < 8*FIN/8; t += 256){
      uint4 u4 = ((const uint4*)xu)[t];
      float* o = &xl[t*8];
      bf2x(u4.x,o[0],o[1]); bf2x(u4.y,o[2],o[3]); bf2x(u4.z,o[4],o[5]); bf2x(u4.w,o[6],o[7]);
    }
  } else {
    const float* xf = (const float*)xr + (size_t)(b*N + i0)*FIN;
    for (int t4 = tid; t4 < 8*FIN/4; t4 += 256)
      *(float4*)&xl[t4*4] = ((const float4*)xf)[t4];
  }
  __syncthreads();
  int f = tid;
  float acc[8] = {0,0,0,0,0,0,0,0};
  if (mode){
    const unsigned short* Wu = (const unsigned short*)Wp;
    for (int c = 0; c < FIN; c += 4){
      float w0 = bf16_to_f32(Wu[(c+0)*FOUT + f]);
      float w1 = bf16_to_f32(Wu[(c+1)*FOUT + f]);
      float w2 = bf16_to_f32(Wu[(c+2)*FOUT + f]);
      float w3 = bf16_to_f32(Wu[(c+3)*FOUT + f]);
      #pragma unroll
      for (int r = 0; r < 8; ++r){
        float4 x4 = *(const float4*)&xl[r*FIN + c];
        acc[r] += x4.x*w0 + x4.y*w1 + x4.z*w2 + x4.w*w3;
      }
    }
  } else {
    const float* Wf = (const float*)Wp;
    for (int c = 0; c < FIN; c += 4){
      float w0 = Wf[(c+0)*FOUT + f];
      float w1 = Wf[(c+1)*FOUT + f];
      float w2 = Wf[(c+2)*FOUT + f];
      float w3 = Wf[(c+3)*FOUT + f];
      #pragma unroll
      for (int r = 0; r < 8; ++r){
        float4 x4 = *(const float4*)&xl[r*FIN + c];
        acc[r] += x4.x*w0 + x4.y*w1 + x4.z*w2 + x4.w*w3;
      }
    }
  }
  float fw = ldf(fccwp, f, mode);
  #pragma unroll
  for (int r = 0; r < 8; ++r){
    ws[O_H + (b*N + i0 + r)*FOUT + f] = acc[r];
    hrow[r*FOUT + f] = acc[r];
  }
  #pragma unroll
  for (int r = 0; r < 8; ++r){
    float v = acc[r] * fw;
    for (int off = 32; off; off >>= 1) v += __shfl_down(v, off);
    if ((tid & 63) == 0) red[(tid >> 6)*8 + r] = v;
  }
  __syncthreads();
  if (tid < 8){
    float s = red[tid] + red[8+tid] + red[16+tid] + red[24+tid];
    ws[O_S + b*N + i0 + tid] = s;
  }
  // P/Q into LDS (4 waves: which = P/Q, hh = row-half); hrow reads wave-uniform
  {
    int o = tid & 63, which = (tid >> 6) & 1, hh = tid >> 7;
    float a4[4] = {0.f,0.f,0.f,0.f};
    if (mode){
      const unsigned short* Au = (const unsigned short*)Ap;
      for (int c = 0; c < FOUT; c += 4){
        float w0 = bf16_to_f32(Au[(which*FOUT + c+0)*EOUT + o]);
        float w1 = bf16_to_f32(Au[(which*FOUT + c+1)*EOUT + o]);
        float w2 = bf16_to_f32(Au[(which*FOUT + c+2)*EOUT + o]);
        float w3 = bf16_to_f32(Au[(which*FOUT + c+3)*EOUT + o]);
        #pragma unroll
        for (int r = 0; r < 4; ++r){
          float4 h4 = *(const float4*)&hrow[(hh*4+r)*FOUT + c];
          a4[r] += h4.x*w0 + h4.y*w1 + h4.z*w2 + h4.w*w3;
        }
      }
    } else {
      const float* Af = (const float*)Ap;
      for (int c = 0; c < FOUT; c += 4){
        float w0 = Af[(which*FOUT + c+0)*EOUT + o];
        float w1 = Af[(which*FOUT + c+1)*EOUT + o];
        float w2 = Af[(which*FOUT + c+2)*EOUT + o];
        float w3 = Af[(which*FOUT + c+3)*EOUT + o];
        #pragma unroll
        for (int r = 0; r < 4; ++r){
          float4 h4 = *(const float4*)&hrow[(hh*4+r)*FOUT + c];
          a4[r] += h4.x*w0 + h4.y*w1 + h4.z*w2 + h4.w*w3;
        }
      }
    }
    float* dst = which ? ql : pl;
    #pragma unroll
    for (int r = 0; r < 4; ++r) dst[(hh*4+r)*EOUT + o] = a4[r];
  }
  __syncthreads();
  // su for rows i0..i0+7 ; sv for pairs (value keyed by j2=(2r)&127; sv[r]==sv[r+64])
  {
    int o = tid & 63, w = tid >> 6;
    float fw2 = ldf(fcwp, o, mode);
    float s1 = lrelu(pl[w*EOUT + o]     + ql[w*EOUT + o])     * fw2;
    float s2 = lrelu(pl[(w+4)*EOUT + o] + ql[(w+4)*EOUT + o]) * fw2;
    float s3 = lrelu(pl[(2*w)*EOUT + o] + ql[(2*w+1)*EOUT + o]) * fw2;
    for (int off = 32; off; off >>= 1){
      s1 += __shfl_down(s1, off); s2 += __shfl_down(s2, off); s3 += __shfl_down(s3, off);
    }
    if (o == 0){
      ws[O_SU + b*N + i0 + w]     = s1;
      ws[O_SU + b*N + i0 + w + 4] = s2;
      int r1 = (i0 + 2*w) >> 1;
      ws[O_SV + b*N + r1]      = s3;
      ws[O_SV + b*N + r1 + 64] = s3;
    }
  }
}

struct AttArgs { const void *we,*x,*wfcw,*wfcb,*fcw,*fcb,*fccb,*wihf,*bihf,*bhhf,*wihb,*bihb,*bhhb; };

// K2: per block: TWO (b,i) rows. edge-MLP + mask + softmax -> att ; hn_pre ; z
__global__ __launch_bounds__(256) void k_att(AttArgs A, const int* __restrict__ adj,
                                             float* __restrict__ ws){
  int blk = blockIdx.x, tid = threadIdx.x;
  int half = tid >> 7, j = tid & 127, wv = (tid >> 6) & 1;
  int tau = blk*2 + half;
  int b = tau >> 7, i = tau & 127;
  __shared__ __align__(16) float wel[2][N*BINW];
  __shared__ __align__(16) float hnp[2][N];
  __shared__ __align__(16) float wfcwl[BINW*BOUT];
  __shared__ __align__(16) float wfcbl[BOUT];
  __shared__ __align__(16) float fcw2l[BOUT];
  __shared__ float red2[2][2];
  int mode = blk_mode(A.x, 256, tid);
  for (int t = tid; t < BINW*BOUT; t += 256) wfcwl[t] = ldf(A.wfcw, t, mode);
  if (tid < BOUT){ wfcbl[tid] = ldf(A.wfcb, tid, mode); fcw2l[tid] = ldf(A.fcw, EOUT + tid, mode); }
  if (mode){
    const unsigned short* weu = (const unsigned short*)A.we + (size_t)(b*N + i)*N*BINW;
    for (int t = j; t < N*BINW/8; t += 128){
      uint4 q = ((const uint4*)weu)[t];
      float* o = &wel[half][t*8];
      bf2x(q.x,o[0],o[1]); bf2x(q.y,o[2],o[3]); bf2x(q.z,o[4],o[5]); bf2x(q.w,o[6],o[7]);
    }
  } else {
    const float* wef = (const float*)A.we + (size_t)(b*N + i)*N*BINW;
    for (int t4 = j; t4 < N*BINW/4; t4 += 128)
      *(float4*)&wel[half][t4*4] = ((const float4*)wef)[t4];
  }
  __syncthreads();
  float wr[BINW];
  #pragma unroll
  for (int t = 0; t < BINW; ++t) wr[t] = wel[half][j*BINW + t];
  float wcon = 0.f;
  for (int o = 0; o < BOUT; o += 4){
    float4 bb = *(const float4*)&wfcbl[o];
    float w0 = bb.x, w1 = bb.y, w2 = bb.z, w3 = bb.w;
    #pragma unroll
    for (int t = 0; t < BINW; ++t){
      float4 w4 = *(const float4*)&wfcwl[t*BOUT + o];
      w0 = fmaf(wr[t], w4.x, w0); w1 = fmaf(wr[t], w4.y, w1);
      w2 = fmaf(wr[t], w4.z, w2); w3 = fmaf(wr[t], w4.w, w3);
    }
    float4 f4 = *(const float4*)&fcw2l[o];
    wcon += lrelu(w0)*f4.x + lrelu(w1)*f4.y + lrelu(w2)*f4.z + lrelu(w3)*f4.w;
  }
  const float* R = ws;
  float econ = (i < 64) ? R[O_SU + b*N + 2*i + (j >= 64 ? 1 : 0)]
                        : R[O_SV + b*N + j];
  float etot = econ + wcon + ldf(A.fcb, 0, mode);
  float m = (adj[(b*N + i)*N + j] > 0) ? etot : -9e15f;
  float mx = m;
  for (int off = 32; off; off >>= 1) mx = fmaxf(mx, __shfl_xor(mx, off));
  if ((tid & 63) == 0) red2[half][wv] = mx;
  __syncthreads();
  mx = fmaxf(red2[half][0], red2[half][1]);
  float ev = expf(m - mx);
  float sum = ev;
  for (int off = 32; off; off >>= 1) sum += __shfl_xor(sum, off);
  __syncthreads();
  if ((tid & 63) == 0) red2[half][wv] = sum;
  __syncthreads();
  sum = red2[half][0] + red2[half][1];
  float att = ev / sum;
  ws[O_ATT + (b*N + i)*N + j] = att;
  float sbi = R[O_S + b*N + i];
  hnp[half][j] = lrelu(att * sbi + ldf(A.fccb, 0, mode));
  __syncthreads();
  // z[b,i,c] both directions (per half: 2 waves = 2 directions)
  {
    int d = wv, c = tid & 63;
    float acc = ldf(d ? A.bihb : A.bihf, c, mode) + ldf(d ? A.bhhb : A.bhhf, c, mode);
    const void* wihp = d ? A.wihb : A.wihf;
    if (mode){
      const uint4* wq = (const uint4*)((const unsigned short*)wihp + c*N);
      #pragma unroll 4
      for (int k = 0; k < N; k += 8){
        uint4 q = wq[k >> 3];
        float w0,w1,w2,w3,w4,w5,w6,w7;
        bf2x(q.x,w0,w1); bf2x(q.y,w2,w3); bf2x(q.z,w4,w5); bf2x(q.w,w6,w7);
        float4 h0 = *(const float4*)&hnp[half][k];
        float4 h1 = *(const float4*)&hnp[half][k+4];
        acc += h0.x*w0 + h0.y*w1 + h0.z*w2 + h0.w*w3
             + h1.x*w4 + h1.y*w5 + h1.z*w6 + h1.w*w7;
      }
    } else {
      const float* wf = (const float*)wihp + c*N;
      #pragma unroll 8
      for (int k = 0; k < N; k += 4){
        float4 h4 = *(const float4*)&hnp[half][k];
        float4 w4 = *(const float4*)&wf[k];
        acc += h4.x*w4.x + h4.y*w4.y + h4.z*w4.z + h4.w*w4.w;
      }
    }
    ws[(d ? O_ZB : O_ZF) + (b*N + i)*CI + c] = acc;
  }
}

// K3: blocks 0..31: serial RNN chains (wave 0).  blocks 32..255: h1 = att@h.
// Independent work -> no sync needed; h1 hides under the chain's latency.
__global__ __launch_bounds__(256, 1) void k_rnn_h1(const void* __restrict__ xr,
                                                   const void* __restrict__ whhf,
                                                   const void* __restrict__ whhb,
                                                   float* __restrict__ ws){
  __shared__ __align__(16) float sh[N*CI];   // rnn: z/h buffer (32 KB); h1: attT (first 4 KB)
  int blk = blockIdx.x, tid = threadIdx.x;
  int mode = blk_mode(xr, 256, tid);
  const float* R = ws;
  if (blk < 32){
    int d = blk >> 4, b = blk & 15;
    const int zb = (d ? O_ZB : O_ZF) + b*N*CI;
    const int ob = (d ? O_RB : O_RF) + b*N*CI;
    for (int it = tid; it < N*CI/4; it += 256)
      *(float4*)&sh[it*4] = *(const float4*)&ws[zb + it*4];
    __syncthreads();
    if (tid < 64){
      int c = tid;
      const void* whhp = d ? whhb : whhf;
      float wreg[CI];
      if (mode){
        const uint4* wq = (const uint4*)((const unsigned short*)whhp + c*CI);
        #pragma unroll
        for (int k = 0; k < CI; k += 8){
          uint4 q = wq[k >> 3];
          bf2x(q.x,wreg[k+0],wreg[k+1]); bf2x(q.y,wreg[k+2],wreg[k+3]);
          bf2x(q.z,wreg[k+4],wreg[k+5]); bf2x(q.w,wreg[k+6],wreg[k+7]);
        }
      } else {
        const float* wf = (const float*)whhp + c*CI;
        #pragma unroll
        for (int k = 0; k < CI; k += 4){
          float4 w4 = *(const float4*)&wf[k];
          wreg[k]=w4.x; wreg[k+1]=w4.y; wreg[k+2]=w4.z; wreg[k+3]=w4.w;
        }
      }
      const int step = d ? -1 : 1;
      int tt = d ? (N-1) : 0;
      float hv = 0.f;
      float z = sh[tt*CI + c];    // single wave: DS ops in-order, no barrier needed
      for (int t = 0; t < N; ++t){
        int ti = tt + step; ti = ti < 0 ? 0 : (ti > N-1 ? N-1 : ti);
        float znext = sh[ti*CI + c];
        float s[CI];
        #pragma unroll
        for (int k = 0; k < CI; ++k) s[k] = bcastf(hv, k);   // batched readlanes
#if __has_builtin(__builtin_amdgcn_sched_barrier)
        __builtin_amdgcn_sched_barrier(0);
#endif
        float a0 = z, a1 = 0.f, a2 = 0.f, a3 = 0.f;
        #pragma unroll
        for (int k = 0; k < CI; k += 4){
          a0 = fmaf(s[k+0], wreg[k+0], a0);
          a1 = fmaf(s[k+1], wreg[k+1], a1);
          a2 = fmaf(s[k+2], wreg[k+2], a2);
          a3 = fmaf(s[k+3], wreg[k+3], a3);
        }
        float x = (a0+a1)+(a2+a3);
        x = fminf(15.f, fmaxf(-15.f, x));
        float p = __expf(2.f * x);
        hv = (p - 1.f) * __builtin_amdgcn_rcpf(p + 1.f);
        sh[tt*CI + c] = hv;
        z = znext;
        tt += step;
      }
    }
    __syncthreads();
    for (int it = tid; it < N*CI/4; it += 256)
      *(float4*)&ws[ob + it*4] = *(const float4*)&sh[it*4];
  } else {
    for (int task = blk - 32; task < 256; task += 224){
      int b = task >> 4, i0 = (task & 15) * 8;
      int f = tid;
      __syncthreads();
      for (int t = tid; t < 8*N; t += 256){
        int r = t >> 7, k = t & 127;
        sh[k*8 + r] = R[O_ATT + (b*N + i0 + r)*N + k];
      }
      __syncthreads();
      float acc[8] = {0,0,0,0,0,0,0,0};
      for (int k = 0; k < N; ++k){
        float hv = R[O_H + (b*N + k)*FOUT + f];
        float4 a0 = *(const float4*)&sh[k*8];
        float4 a1 = *(const float4*)&sh[k*8 + 4];
        acc[0] += a0.x*hv; acc[1] += a0.y*hv; acc[2] += a0.z*hv; acc[3] += a0.w*hv;
        acc[4] += a1.x*hv; acc[5] += a1.y*hv; acc[6] += a1.z*hv; acc[7] += a1.w*hv;
      }
      #pragma unroll
      for (int r = 0; r < 8; ++r)
        ws[O_H1 + (b*N + i0 + r)*FOUT + f] = acc[r];
    }
  }
}

// K4: out = elu(cat(lrelu(rf), lrelu(rb), h1) @ fco_w + fco_b), 8 rows/block
__global__ __launch_bounds__(256) void k_out(const void* __restrict__ xr,
                                             const void* __restrict__ fcowp,
                                             const void* __restrict__ fcobp,
                                             const float* __restrict__ R, void* dout){
  int blk = blockIdx.x, tid = threadIdx.x;
  int b = blk >> 4, i0 = (blk & 15) * 8;
  constexpr int KW = 2*CI + FOUT;  // 416
  __shared__ __align__(16) float inl[8*KW];
  int mode = blk_mode(xr, 256, tid);
  for (int t = tid; t < 8*2*CI; t += 256){
    int r = t >> 7, k = t & 127;
    int row = b*N + i0 + r;
    inl[r*KW + k] = (k < CI) ? lrelu(R[O_RF + row*CI + k])
                             : lrelu(R[O_RB + row*CI + (k - CI)]);
  }
  for (int t = tid; t < 8*FOUT; t += 256){
    int r = t >> 8, k = t & 255;
    inl[r*KW + 2*CI + k] = R[O_H1 + (b*N + i0 + r)*FOUT + k];
  }
  __syncthreads();
  int l = tid;
  float bias = ldf(fcobp, l, mode);
  float acc[8];
  #pragma unroll
  for (int r = 0; r < 8; ++r) acc[r] = bias;
  if (mode){
    const unsigned short* fu = (const unsigned short*)fcowp;
    for (int k = 0; k < KW; k += 4){
      float w0 = bf16_to_f32(fu[(k+0)*L1 + l]);
      float w1 = bf16_to_f32(fu[(k+1)*L1 + l]);
      float w2 = bf16_to_f32(fu[(k+2)*L1 + l]);
      float w3 = bf16_to_f32(fu[(k+3)*L1 + l]);
      #pragma unroll
      for (int r = 0; r < 8; ++r){
        float4 v = *(const float4*)&inl[r*KW + k];
        acc[r] += v.x*w0 + v.y*w1 + v.z*w2 + v.w*w3;
      }
    }
  } else {
    const float* ff = (const float*)fcowp;
    for (int k = 0; k < KW; k += 4){
      float w0 = ff[(k+0)*L1 + l];
      float w1 = ff[(k+1)*L1 + l];
      float w2 = ff[(k+2)*L1 + l];
      float w3 = ff[(k+3)*L1 + l];
      #pragma unroll
      for (int r = 0; r < 8; ++r){
        float4 v = *(const float4*)&inl[r*KW + k];
        acc[r] += v.x*w0 + v.y*w1 + v.z*w2 + v.w*w3;
      }
    }
  }
  #pragma unroll
  for (int r = 0; r < 8; ++r){
    float o = acc[r] > 0.f ? acc[r] : expm1f(acc[r]);
    int idx = (b*N + i0 + r)*L1 + l;
    if (mode) ((__hip_bfloat16*)dout)[idx] = __float2bfloat16(o);
    else      ((float*)dout)[idx] = o;
  }
}

extern "C" void kernel_launch(void* const* d_in, const int* in_sizes, int n_in,
                              void* d_out, int out_size, void* d_ws, size_t ws_size,
                              hipStream_t stream){
  (void)in_sizes; (void)n_in; (void)out_size; (void)ws_size;
  float* ws = (float*)d_ws;
  AttArgs A;
  A.we = d_in[2]; A.x = d_in[0]; A.wfcw = d_in[5]; A.wfcb = d_in[6];
  A.fcw = d_in[7]; A.fcb = d_in[8]; A.fccb = d_in[10];
  A.wihf = d_in[11]; A.bihf = d_in[13]; A.bhhf = d_in[14];
  A.wihb = d_in[15]; A.bihb = d_in[17]; A.bhhb = d_in[18];
  hipLaunchKernelGGL(k_h_pq,   dim3(256),    dim3(256), 0, stream,
                     d_in[0], d_in[3], d_in[4], d_in[9], d_in[7], ws);
  hipLaunchKernelGGL(k_att,    dim3(B*N/2),  dim3(256), 0, stream, A, (const int*)d_in[1], ws);
  hipLaunchKernelGGL(k_rnn_h1, dim3(256),    dim3(256), 0, stream,
                     d_in[0], d_in[12], d_in[16], ws);
  hipLaunchKernelGGL(k_out,    dim3(256),    dim3(256), 0, stream,
                     d_in[0], d_in[19], d_in[20], ws, d_out);
}